// Round 17
// baseline (212.505 us; speedup 1.0000x reference)
//
#include <hip/hip_runtime.h>

// x: (128, 256, 28, 28) fp32.  b=16, t=8, c=256, h=w=28, p=4, ph=pw=7, e=4096.
// y1u (ws): single bf16 plane [bt*49 rows][pitch 4128], e' = c*16 + p1*4 + p2.
// Pitch 4128 (8256 B = odd multiple of 64 B) breaks pow-2 channel aliasing.

#define IDX36(a,b) ((((a)*8)+(b))-((((a)*((a)+1)))/2))
#define YP 4128

typedef __attribute__((ext_vector_type(8)))  short bf16x8;   // 8 bf16 (4 VGPRs)
typedef __attribute__((ext_vector_type(16))) float f32x16;   // 32x32 MFMA acc

__device__ __forceinline__ float wsum64(float v){
  #pragma unroll
  for (int off=32; off; off>>=1) v += __shfl_xor(v, off);
  return v;
}
__device__ __forceinline__ float wsum32(float v){
  #pragma unroll
  for (int off=16; off; off>>=1) v += __shfl_xor(v, off);
  return v;
}
__device__ __forceinline__ unsigned int rne_bf16(float f){
  unsigned int b = __float_as_uint(f);
  return (b + 0x7FFFu + ((b>>16)&1u)) >> 16;
}

// ---------------- temporal stage 1: partial Grams per c-slice ----------------
__global__ __launch_bounds__(256) void k_t1(const float* __restrict__ x, float* __restrict__ wsG){
  const int bx = blockIdx.x;
  const int b = bx / 112;
  const int ph = (bx % 112) / 16;
  const int slice = bx & 15;
  const int c0 = slice * 16;
  const int tid = threadIdx.x;

  __shared__ float lds[8*16*116];   // [t][c][116-padded stripe of 112 floats]
  const float4* x4 = reinterpret_cast<const float4*>(x);

  #pragma unroll
  for (int t=0;t<8;t++){
    const int base = ((b*8+t)*256 + c0)*196 + ph*28;
    {
      const int f = tid, c = f/28, m = f%28;
      *reinterpret_cast<float4*>(&lds[(t*16+c)*116 + m*4]) = x4[base + c*196 + m];
    }
    if (tid < 192){
      const int f = 256+tid, c = f/28, m = f%28;
      *reinterpret_cast<float4*>(&lds[(t*16+c)*116 + m*4]) = x4[base + c*196 + m];
    }
  }
  __syncthreads();

  const int pw   = tid >> 5;        // 0..6 valid; group 7 is idle-compute
  const int slot = tid & 31;
  const int c    = slot >> 1;
  const int p1b  = (slot & 1) * 2;

  float v[8][8];
  #pragma unroll
  for (int t=0;t<8;t++){
    const float* p = &lds[(t*16+c)*116 + p1b*28 + pw*4];
    const float4 a  = *reinterpret_cast<const float4*>(p);
    const float4 b2 = *reinterpret_cast<const float4*>(p + 28);
    v[t][0]=a.x;  v[t][1]=a.y;  v[t][2]=a.z;  v[t][3]=a.w;
    v[t][4]=b2.x; v[t][5]=b2.y; v[t][6]=b2.z; v[t][7]=b2.w;
  }

  float Au[36], sm[8];
  #pragma unroll
  for (int a2=0;a2<8;a2++){
    float s0 = 0.f;
    #pragma unroll
    for (int e=0;e<8;e++) s0 += v[a2][e];
    sm[a2] = s0;
    #pragma unroll
    for (int b2=a2;b2<8;b2++){
      float s = 0.f;
      #pragma unroll
      for (int e=0;e<8;e++) s += v[a2][e]*v[b2][e];
      Au[IDX36(a2,b2)] = s;
    }
  }
  #pragma unroll
  for (int i=0;i<36;i++) Au[i] = wsum32(Au[i]);
  #pragma unroll
  for (int t=0;t<8;t++) sm[t] = wsum32(sm[t]);

  if (slot == 0 && pw < 7){
    const int base = ((b*49 + ph*7 + pw)*16 + slice)*44;
    #pragma unroll
    for (int i=0;i<36;i++) wsG[base+i] = Au[i];
    #pragma unroll
    for (int t=0;t<8;t++)  wsG[base+36+t] = sm[t];
  }
}

// ---------------- temporal stage 2: reduce slices, softmax -> W, cc ----------------
__global__ __launch_bounds__(64) void k_t2(const float* __restrict__ wsG, float* __restrict__ wsWt){
  const int seq = blockIdx.x;
  const int lane = threadIdx.x;
  __shared__ float red[44];
  if (lane < 44){
    float a = 0.f;
    #pragma unroll
    for (int s=0;s<16;s++) a += wsG[(seq*16+s)*44 + lane];
    red[lane] = a;
  }
  __syncthreads();
  if (lane < 8){
    const int i = lane;
    float Ar[36], mean[8], rstd[8];
    #pragma unroll
    for (int k=0;k<36;k++) Ar[k] = red[k];
    #pragma unroll
    for (int t=0;t<8;t++){
      const float sv = red[36+t];
      mean[t] = sv * (1.f/4096.f);
      const float var = Ar[IDX36(t,t)] * (1.f/4096.f) - mean[t]*mean[t];
      rstd[t] = rsqrtf(var + 1e-5f);
    }
    #define GV(a,b) ((((a)<8)&&((b)<8)) ? (rstd[(a)]*rstd[(b)]*(Ar[((a)<=(b))?IDX36((a),(b)):IDX36((b),(a))] - 4096.f*mean[(a)]*mean[(b)])) : 0.f)
    float l[8]; float mx = -1e30f;
    #pragma unroll
    for (int j=0;j<8;j++){
      const float sij = GV(i+1,j+1) - GV(i+1,j) - GV(i,j+1) + GV(i,j);
      l[j] = sij * (1.f/64.f);
      mx = fmaxf(mx, l[j]);
    }
    float ss = 0.f;
    #pragma unroll
    for (int j=0;j<8;j++){ l[j] = __expf(l[j]-mx); ss += l[j]; }
    const float inv = 1.f/ss;
    float cc = 0.f;
    #pragma unroll
    for (int k2=0;k2<8;k2++){
      const float q = (((k2>=1)? l[k2-1] : 0.f) - l[k2]) * inv;
      const float wv2 = q * rstd[k2];
      wsWt[seq*72 + i*8 + k2] = wv2;
      cc -= wv2 * mean[k2];
    }
    wsWt[seq*72 + 64 + i] = cc;
    #undef GV
  }
}

// ---------------- temporal stage 3: recombine + write y1 (single bf16 plane, padded pitch) ----------------
__global__ __launch_bounds__(256) void k_t3(const float* __restrict__ x, const float* __restrict__ wsWt,
                                            unsigned short* __restrict__ y1u){
  const int bx = blockIdx.x;
  const int b = bx / 112;
  const int ph = (bx % 112) / 16;
  const int slice = bx & 15;
  const int c0 = slice * 16;
  const int tid = threadIdx.x;

  __shared__ float Wl[7][72];
  for (int idx=tid; idx<504; idx+=256)
    Wl[idx/72][idx%72] = wsWt[(b*49 + ph*7 + idx/72)*72 + idx%72];
  __syncthreads();

  const float4* x4 = reinterpret_cast<const float4*>(x);

  #pragma unroll
  for (int fi=0; fi<2; fi++){
    const int f = fi*256 + tid;
    if (f < 448){
      const int c = f/28, m = f%28, pw = m%7, p1 = m/7;
      float4 v[8];
      #pragma unroll
      for (int t=0;t<8;t++) v[t] = x4[((b*8+t)*256 + c0+c)*196 + ph*28 + m];
      const float* W = Wl[pw];
      const int pp = ph*7 + pw;
      #pragma unroll
      for (int i=0;i<8;i++){
        const float ci = W[64+i];
        float4 o;
        o.x = v[i].x + ci; o.y = v[i].y + ci; o.z = v[i].z + ci; o.w = v[i].w + ci;
        #pragma unroll
        for (int j=0;j<8;j++){
          const float w = W[i*8+j];
          o.x += w*v[j].x; o.y += w*v[j].y; o.z += w*v[j].z; o.w += w*v[j].w;
        }
        const unsigned int h0=rne_bf16(o.x), h1=rne_bf16(o.y), h2=rne_bf16(o.z), h3=rne_bf16(o.w);
        const size_t ybase = (size_t)((b*8+i)*49 + pp)*YP + (c0+c)*16 + p1*4;
        *reinterpret_cast<uint2*>(&y1u[ybase]) = make_uint2(h0|(h1<<16), h2|(h3<<16));
      }
    }
  }
}

// ---------------- spatial stage: Gram partials via MFMA on bf16 y ----------------
__global__ __launch_bounds__(256,3) void k_s1(const unsigned short* __restrict__ y1u, float* __restrict__ wsA){
  const int bt = blockIdx.x >> 2;
  const int slice = blockIdx.x & 3;
  const int tid = threadIdx.x;
  const int wave = tid >> 6, lane = tid & 63;

  __shared__ unsigned short Ah[64*136];
  __shared__ float red[64*52];
  for (int i=tid; i<64*52; i+=256) red[i] = 0.f;

  // pad rows: 49 = ones, 50..63 = zero (constant across chunks)
  for (int idx=tid; idx<15*128; idx+=256){
    const int rr = 49 + idx/128, cc = idx%128;
    Ah[rr*136 + cc] = (rr==49) ? (unsigned short)0x3F80 : (unsigned short)0;
  }

  f32x16 acc00, acc01, acc11;
  #pragma unroll
  for (int i=0;i<16;i++){ acc00[i]=0.f; acc01[i]=0.f; acc11[i]=0.f; }

  const int r0 = lane & 31;
  const int koff = (lane >> 5) * 8;
  const int lrow = tid >> 4;        // 0..15
  const int lq   = tid & 15;        // 16B unit within 256B row-chunk

#define ISSUE(pf, ch) { \
  _Pragma("unroll") \
  for (int p=0;p<4;p++){ \
    const int row = p*16 + lrow; \
    pf[p] = make_uint4(0u,0u,0u,0u); \
    if (row < 49) pf[p] = *reinterpret_cast<const uint4*>(&y1u[(size_t)(bt*49+row)*YP + slice*1024 + (ch)*128 + lq*8]); } }

#define CW(pf) { \
  _Pragma("unroll") \
  for (int p=0;p<4;p++){ \
    const int row = p*16 + lrow; \
    if (row < 49) *reinterpret_cast<uint4*>(&Ah[row*136 + lq*8]) = pf[p]; } }

#define MF() { \
  _Pragma("unroll") \
  for (int kk=0;kk<2;kk++){ \
    const int kw = (wave + kk*4)*16; \
    const bf16x8 f0 = *reinterpret_cast<const bf16x8*>(&Ah[ r0     *136 + kw + koff]); \
    const bf16x8 f1 = *reinterpret_cast<const bf16x8*>(&Ah[(32+r0)*136 + kw + koff]); \
    acc00 = __builtin_amdgcn_mfma_f32_32x32x16_bf16(f0, f0, acc00, 0,0,0); \
    acc01 = __builtin_amdgcn_mfma_f32_32x32x16_bf16(f0, f1, acc01, 0,0,0); \
    acc11 = __builtin_amdgcn_mfma_f32_32x32x16_bf16(f1, f1, acc11, 0,0,0); } }

  uint4 pfA[4], pfB[4];
  ISSUE(pfA, 0);
  #pragma unroll
  for (int ch=0; ch<8; ch+=2){
    if (ch+1<8) ISSUE(pfB, ch+1);
    __syncthreads();                 // prev MFMA done; pads visible on first pass
    CW(pfA);
    __syncthreads();
    MF();
    if (ch+2<8) ISSUE(pfA, ch+2);
    __syncthreads();
    CW(pfB);
    __syncthreads();
    MF();
  }
  __syncthreads();

  // cross-wave reduce (upper tiles): C layout col=lane&31, row=(reg&3)+8*(reg>>2)+4*(lane>>5)
  const int ccol = lane & 31;
  const int rbase = 4*(lane>>5);
  #pragma unroll
  for (int q2=0;q2<16;q2++){
    const int rr = (q2&3) + 8*(q2>>2) + rbase;
    atomicAdd(&red[ rr    *52 + ccol     ], acc00[q2]);
    atomicAdd(&red[ rr    *52 + 32 + ccol], acc01[q2]);
    atomicAdd(&red[(rr+32)*52 + 32 + ccol], acc11[q2]);
  }
  __syncthreads();
  float* wp = wsA + blockIdx.x * 2500;
  for (int idx=tid; idx<2500; idx+=256){
    const int i2 = idx/50, j2 = idx%50;
    wp[idx] = (i2>=32 && j2<32) ? red[j2*52+i2] : red[i2*52+j2];
  }
#undef ISSUE
#undef CW
#undef MF
}

// ---------------- spatial stage: softmax -> WT (+I folded, padded 52), c ----------------
__global__ __launch_bounds__(256) void k_s2(const float* __restrict__ wsA, float* __restrict__ wsWT, float* __restrict__ wsC){
  const int bt = blockIdx.x;
  const int tid = threadIdx.x;
  __shared__ float A[2500];
  __shared__ float m[49], r[49];
  for (int idx=tid; idx<2548; idx+=256) wsWT[bt*2548+idx] = 0.f;
  for (int idx=tid; idx<2500; idx+=256){
    float v = 0.f;
    #pragma unroll
    for (int sl=0; sl<4; sl++) v += wsA[(bt*4+sl)*2500 + idx];
    A[idx] = v;
  }
  __syncthreads();
  if (tid < 49){
    const float mm = A[49*50+tid] * (1.f/4096.f);        // row 49 = ones row -> sums
    const float var = A[tid*50+tid] * (1.f/4096.f) - mm*mm;
    m[tid]=mm; r[tid]=rsqrtf(var+1e-5f);
  }
  __syncthreads();
  const int wv = tid>>6, lane = tid&63;
  for (int i=wv; i<49; i+=4){
    const float ri = r[i], mi = m[i];
    float rv=0.f, mv=0.f, L=-1e30f;
    if (lane < 49){
      rv = r[lane]; mv = m[lane];
      L = ri*rv*(A[i*50+lane] - 4096.f*mi*mv) * (1.f/64.f);
    }
    float mx = L;
    #pragma unroll
    for (int off=32; off; off>>=1) mx = fmaxf(mx, __shfl_xor(mx, off));
    const float p = (lane<49) ? __expf(L-mx) : 0.f;
    const float ss = wsum64(p);
    const float Wv = (p/ss)*rv;
    // WT[j=lane][i] = W[i][j] + I
    if (lane < 49) wsWT[bt*2548 + lane*52 + i] = Wv + ((lane==i) ? 1.f : 0.f);
    const float cp = wsum64(-Wv*mv);
    if (lane == 0) wsC[bt*49+i] = cp;
  }
}

// ---------------- spatial stage: recombine via MFMA, B-frags direct from global (R14 body) ----------------
// O = Wp*Y + c. Single bf16 Y plane: 25 ushort loads + 16 MFMA per tile. (256,4): whole
// grid co-resident (4 blocks/CU) to hide the gather latency — s3 is latency-bound.
__global__ __launch_bounds__(256,4) void k_s3(const unsigned short* __restrict__ y1u, const float* __restrict__ wsWT,
                                              const float* __restrict__ wsC, float* __restrict__ out){
  const int bt = blockIdx.x >> 3;
  const int chunk = blockIdx.x & 7;       // 512 e-cols per block
  const int tid = threadIdx.x;
  const int wave = tid >> 6, lane = tid & 63;

  __shared__ unsigned short Wh[64*68], Wlo[64*68];
  for (int idx=tid; idx<64*64; idx+=256){
    const int i = idx>>6, j = idx&63;
    float v = 0.f;
    if (i < 49){
      if (j < 49)       v = wsWT[bt*2548 + j*52 + i];   // W[i][j]+I
      else if (j == 49) v = wsC[bt*49 + i];             // c[i]
    }
    const unsigned int u = __float_as_uint(v);
    Wh [i*68+j] = (unsigned short)(u>>16);
    Wlo[i*68+j] = (unsigned short)rne_bf16(v - __uint_as_float(u & 0xFFFF0000u));
  }
  __syncthreads();

  const int r0 = lane & 31;
  const int koff = (lane >> 5) * 8;
  bf16x8 A0h[4], A0l[4], A1h[4], A1l[4];
  #pragma unroll
  for (int kk=0;kk<4;kk++){
    const int off = kk*16 + koff;
    A0h[kk] = *reinterpret_cast<const bf16x8*>(&Wh [ r0     *68 + off]);
    A0l[kk] = *reinterpret_cast<const bf16x8*>(&Wlo[ r0     *68 + off]);
    A1h[kk] = *reinterpret_cast<const bf16x8*>(&Wh [(32+r0)*68 + off]);
    A1l[kk] = *reinterpret_cast<const bf16x8*>(&Wlo[(32+r0)*68 + off]);
  }

  const unsigned short* ybu = y1u + (size_t)bt*49*YP;
  float* ob_base = out + bt*200704;
  const bool lo32 = (lane < 32);

  #pragma unroll
  for (int tt=0; tt<4; tt++){
    const int ecol = chunk*512 + (wave*4+tt)*32 + r0;
    const unsigned short* pb = ybu + (size_t)koff*YP + ecol;   // per-lane base at j=koff

    f32x16 acc0, acc1;
    #pragma unroll
    for (int i=0;i<16;i++){ acc0[i]=0.f; acc1[i]=0.f; }

    #pragma unroll
    for (int kk=0;kk<4;kk++){
      bf16x8 Bh;
      if (kk < 3){
        #pragma unroll
        for (int s=0;s<8;s++)             // j = kk*16 + koff + s  (max 47 < 49)
          Bh[s] = (short)pb[(size_t)(kk*16+s)*YP];
      } else {
        // lanes<32: j=48 (load), j=49 (ones: folds c); lanes>=32: all zero
        const unsigned short h48 = lo32 ? pb[(size_t)48*YP] : (unsigned short)0;
        Bh[0] = (short)h48;
        Bh[1] = lo32 ? (short)0x3F80 : (short)0;
        #pragma unroll
        for (int s=2;s<8;s++) Bh[s]=0;
      }
      acc0 = __builtin_amdgcn_mfma_f32_32x32x16_bf16(A0h[kk], Bh, acc0, 0,0,0);
      acc0 = __builtin_amdgcn_mfma_f32_32x32x16_bf16(A0l[kk], Bh, acc0, 0,0,0);
      acc1 = __builtin_amdgcn_mfma_f32_32x32x16_bf16(A1h[kk], Bh, acc1, 0,0,0);
      acc1 = __builtin_amdgcn_mfma_f32_32x32x16_bf16(A1l[kk], Bh, acc1, 0,0,0);
    }

    // store: C layout col=lane&31, row=(reg&3)+8*(reg>>2)+4*(lane>>5)
    const int c  = ecol >> 4;
    const int p1 = (ecol >> 2) & 3;
    const int p2 = ecol & 3;
    float* ob = ob_base + c*784 + p1*28 + p2;
    const int rbase = 4*(lane>>5);
    #pragma unroll
    for (int q=0;q<16;q++){
      const int i0 = (q&3) + 8*(q>>2) + rbase;       // 0..31
      ob[(i0/7)*112 + (i0%7)*4] = acc0[q];
      const int i1 = 32 + i0;
      if (i1 < 49) ob[(i1/7)*112 + (i1%7)*4] = acc1[q];
    }
  }
}

extern "C" void kernel_launch(void* const* d_in, const int* in_sizes, int n_in,
                              void* d_out, int out_size, void* d_ws, size_t ws_size,
                              hipStream_t stream) {
  const float* x = (const float*)d_in[0];
  float* out = (float*)d_out;
  float* ws  = (float*)d_ws;
  unsigned short* y1u = (unsigned short*)ws;  // 6272 rows * 4128 bf16 = 51.8 MB
  float* wsA  = ws + 13000000;          // 512*2500 = 1,280,000 floats (after y1u + slack)
  float* wsWT = wsA + 512*2500;         // 128*2548 = 326,144 floats (W^T + I, padded 52)
  float* wsC  = wsWT + 128*2548;        // 128*49   -> total ~58.6 MB (well within ws)
  // overlay (dead before k_s1 writes wsA): temporal Gram partials + per-seq W
  float* wsG  = wsA;                    // 784*16*44 = 551,936 floats
  float* wsWt = wsA + 551936;           // 784*72   =  56,448 floats (fits in wsA)
  hipLaunchKernelGGL(k_t1, dim3(1792), dim3(256), 0, stream, x, wsG);
  hipLaunchKernelGGL(k_t2, dim3(784),  dim3(64),  0, stream, wsG, wsWt);
  hipLaunchKernelGGL(k_t3, dim3(1792), dim3(256), 0, stream, x, wsWt, y1u);
  hipLaunchKernelGGL(k_s1, dim3(512),  dim3(256), 0, stream, y1u, wsA);
  hipLaunchKernelGGL(k_s2, dim3(128),  dim3(256), 0, stream, wsA, wsWT, wsC);
  hipLaunchKernelGGL(k_s3, dim3(1024), dim3(256), 0, stream, y1u, wsWT, wsC, out);
}

// Round 18
// 182.770 us; speedup vs baseline: 1.1627x; 1.1627x over previous
//
#include <hip/hip_runtime.h>

// x: (128, 256, 28, 28) fp32.  b=16, t=8, c=256, h=w=28, p=4, ph=pw=7, e=4096.
// y1u (ws): single bf16 plane [bt*49 rows][pitch 4128], e' = c*16 + p1*4 + p2.
// Pitch 4128 (8256 B = odd multiple of 64 B) breaks pow-2 channel aliasing.

#define IDX36(a,b) ((((a)*8)+(b))-((((a)*((a)+1)))/2))
#define YP 4128

typedef __attribute__((ext_vector_type(8)))  short bf16x8;   // 8 bf16 (4 VGPRs)
typedef __attribute__((ext_vector_type(16))) float f32x16;   // 32x32 MFMA acc

__device__ __forceinline__ float wsum64(float v){
  #pragma unroll
  for (int off=32; off; off>>=1) v += __shfl_xor(v, off);
  return v;
}
__device__ __forceinline__ float wsum32(float v){
  #pragma unroll
  for (int off=16; off; off>>=1) v += __shfl_xor(v, off);
  return v;
}
__device__ __forceinline__ unsigned int rne_bf16(float f){
  unsigned int b = __float_as_uint(f);
  return (b + 0x7FFFu + ((b>>16)&1u)) >> 16;
}

// ---------------- temporal stage 1: partial Grams per c-slice ----------------
__global__ __launch_bounds__(256) void k_t1(const float* __restrict__ x, float* __restrict__ wsG){
  const int bx = blockIdx.x;
  const int b = bx / 112;
  const int ph = (bx % 112) / 16;
  const int slice = bx & 15;
  const int c0 = slice * 16;
  const int tid = threadIdx.x;

  __shared__ float lds[8*16*116];   // [t][c][116-padded stripe of 112 floats]
  const float4* x4 = reinterpret_cast<const float4*>(x);

  #pragma unroll
  for (int t=0;t<8;t++){
    const int base = ((b*8+t)*256 + c0)*196 + ph*28;
    {
      const int f = tid, c = f/28, m = f%28;
      *reinterpret_cast<float4*>(&lds[(t*16+c)*116 + m*4]) = x4[base + c*196 + m];
    }
    if (tid < 192){
      const int f = 256+tid, c = f/28, m = f%28;
      *reinterpret_cast<float4*>(&lds[(t*16+c)*116 + m*4]) = x4[base + c*196 + m];
    }
  }
  __syncthreads();

  const int pw   = tid >> 5;        // 0..6 valid; group 7 is idle-compute
  const int slot = tid & 31;
  const int c    = slot >> 1;
  const int p1b  = (slot & 1) * 2;

  float v[8][8];
  #pragma unroll
  for (int t=0;t<8;t++){
    const float* p = &lds[(t*16+c)*116 + p1b*28 + pw*4];
    const float4 a  = *reinterpret_cast<const float4*>(p);
    const float4 b2 = *reinterpret_cast<const float4*>(p + 28);
    v[t][0]=a.x;  v[t][1]=a.y;  v[t][2]=a.z;  v[t][3]=a.w;
    v[t][4]=b2.x; v[t][5]=b2.y; v[t][6]=b2.z; v[t][7]=b2.w;
  }

  float Au[36], sm[8];
  #pragma unroll
  for (int a2=0;a2<8;a2++){
    float s0 = 0.f;
    #pragma unroll
    for (int e=0;e<8;e++) s0 += v[a2][e];
    sm[a2] = s0;
    #pragma unroll
    for (int b2=a2;b2<8;b2++){
      float s = 0.f;
      #pragma unroll
      for (int e=0;e<8;e++) s += v[a2][e]*v[b2][e];
      Au[IDX36(a2,b2)] = s;
    }
  }
  #pragma unroll
  for (int i=0;i<36;i++) Au[i] = wsum32(Au[i]);
  #pragma unroll
  for (int t=0;t<8;t++) sm[t] = wsum32(sm[t]);

  if (slot == 0 && pw < 7){
    const int base = ((b*49 + ph*7 + pw)*16 + slice)*44;
    #pragma unroll
    for (int i=0;i<36;i++) wsG[base+i] = Au[i];
    #pragma unroll
    for (int t=0;t<8;t++)  wsG[base+36+t] = sm[t];
  }
}

// ---------------- temporal stage 2: reduce slices, softmax -> W, cc ----------------
__global__ __launch_bounds__(64) void k_t2(const float* __restrict__ wsG, float* __restrict__ wsWt){
  const int seq = blockIdx.x;
  const int lane = threadIdx.x;
  __shared__ float red[44];
  if (lane < 44){
    float a = 0.f;
    #pragma unroll
    for (int s=0;s<16;s++) a += wsG[(seq*16+s)*44 + lane];
    red[lane] = a;
  }
  __syncthreads();
  if (lane < 8){
    const int i = lane;
    float Ar[36], mean[8], rstd[8];
    #pragma unroll
    for (int k=0;k<36;k++) Ar[k] = red[k];
    #pragma unroll
    for (int t=0;t<8;t++){
      const float sv = red[36+t];
      mean[t] = sv * (1.f/4096.f);
      const float var = Ar[IDX36(t,t)] * (1.f/4096.f) - mean[t]*mean[t];
      rstd[t] = rsqrtf(var + 1e-5f);
    }
    #define GV(a,b) ((((a)<8)&&((b)<8)) ? (rstd[(a)]*rstd[(b)]*(Ar[((a)<=(b))?IDX36((a),(b)):IDX36((b),(a))] - 4096.f*mean[(a)]*mean[(b)])) : 0.f)
    float l[8]; float mx = -1e30f;
    #pragma unroll
    for (int j=0;j<8;j++){
      const float sij = GV(i+1,j+1) - GV(i+1,j) - GV(i,j+1) + GV(i,j);
      l[j] = sij * (1.f/64.f);
      mx = fmaxf(mx, l[j]);
    }
    float ss = 0.f;
    #pragma unroll
    for (int j=0;j<8;j++){ l[j] = __expf(l[j]-mx); ss += l[j]; }
    const float inv = 1.f/ss;
    float cc = 0.f;
    #pragma unroll
    for (int k2=0;k2<8;k2++){
      const float q = (((k2>=1)? l[k2-1] : 0.f) - l[k2]) * inv;
      const float wv2 = q * rstd[k2];
      wsWt[seq*72 + i*8 + k2] = wv2;
      cc -= wv2 * mean[k2];
    }
    wsWt[seq*72 + 64 + i] = cc;
    #undef GV
  }
}

// ---------------- temporal stage 3: recombine + write y1 (single bf16 plane, padded pitch) ----------------
__global__ __launch_bounds__(256) void k_t3(const float* __restrict__ x, const float* __restrict__ wsWt,
                                            unsigned short* __restrict__ y1u){
  const int bx = blockIdx.x;
  const int b = bx / 112;
  const int ph = (bx % 112) / 16;
  const int slice = bx & 15;
  const int c0 = slice * 16;
  const int tid = threadIdx.x;

  __shared__ float Wl[7][72];
  for (int idx=tid; idx<504; idx+=256)
    Wl[idx/72][idx%72] = wsWt[(b*49 + ph*7 + idx/72)*72 + idx%72];
  __syncthreads();

  const float4* x4 = reinterpret_cast<const float4*>(x);

  #pragma unroll
  for (int fi=0; fi<2; fi++){
    const int f = fi*256 + tid;
    if (f < 448){
      const int c = f/28, m = f%28, pw = m%7, p1 = m/7;
      float4 v[8];
      #pragma unroll
      for (int t=0;t<8;t++) v[t] = x4[((b*8+t)*256 + c0+c)*196 + ph*28 + m];
      const float* W = Wl[pw];
      const int pp = ph*7 + pw;
      #pragma unroll
      for (int i=0;i<8;i++){
        const float ci = W[64+i];
        float4 o;
        o.x = v[i].x + ci; o.y = v[i].y + ci; o.z = v[i].z + ci; o.w = v[i].w + ci;
        #pragma unroll
        for (int j=0;j<8;j++){
          const float w = W[i*8+j];
          o.x += w*v[j].x; o.y += w*v[j].y; o.z += w*v[j].z; o.w += w*v[j].w;
        }
        const unsigned int h0=rne_bf16(o.x), h1=rne_bf16(o.y), h2=rne_bf16(o.z), h3=rne_bf16(o.w);
        const size_t ybase = (size_t)((b*8+i)*49 + pp)*YP + (c0+c)*16 + p1*4;
        *reinterpret_cast<uint2*>(&y1u[ybase]) = make_uint2(h0|(h1<<16), h2|(h3<<16));
      }
    }
  }
}

// ---------------- spatial stage: Gram partials via MFMA on bf16 y ----------------
__global__ __launch_bounds__(256,3) void k_s1(const unsigned short* __restrict__ y1u, float* __restrict__ wsA){
  const int bt = blockIdx.x >> 2;
  const int slice = blockIdx.x & 3;
  const int tid = threadIdx.x;
  const int wave = tid >> 6, lane = tid & 63;

  __shared__ unsigned short Ah[64*136];
  __shared__ float red[64*52];
  for (int i=tid; i<64*52; i+=256) red[i] = 0.f;

  // pad rows: 49 = ones, 50..63 = zero (constant across chunks)
  for (int idx=tid; idx<15*128; idx+=256){
    const int rr = 49 + idx/128, cc = idx%128;
    Ah[rr*136 + cc] = (rr==49) ? (unsigned short)0x3F80 : (unsigned short)0;
  }

  f32x16 acc00, acc01, acc11;
  #pragma unroll
  for (int i=0;i<16;i++){ acc00[i]=0.f; acc01[i]=0.f; acc11[i]=0.f; }

  const int r0 = lane & 31;
  const int koff = (lane >> 5) * 8;
  const int lrow = tid >> 4;        // 0..15
  const int lq   = tid & 15;        // 16B unit within 256B row-chunk

#define ISSUE(pf, ch) { \
  _Pragma("unroll") \
  for (int p=0;p<4;p++){ \
    const int row = p*16 + lrow; \
    pf[p] = make_uint4(0u,0u,0u,0u); \
    if (row < 49) pf[p] = *reinterpret_cast<const uint4*>(&y1u[(size_t)(bt*49+row)*YP + slice*1024 + (ch)*128 + lq*8]); } }

#define CW(pf) { \
  _Pragma("unroll") \
  for (int p=0;p<4;p++){ \
    const int row = p*16 + lrow; \
    if (row < 49) *reinterpret_cast<uint4*>(&Ah[row*136 + lq*8]) = pf[p]; } }

#define MF() { \
  _Pragma("unroll") \
  for (int kk=0;kk<2;kk++){ \
    const int kw = (wave + kk*4)*16; \
    const bf16x8 f0 = *reinterpret_cast<const bf16x8*>(&Ah[ r0     *136 + kw + koff]); \
    const bf16x8 f1 = *reinterpret_cast<const bf16x8*>(&Ah[(32+r0)*136 + kw + koff]); \
    acc00 = __builtin_amdgcn_mfma_f32_32x32x16_bf16(f0, f0, acc00, 0,0,0); \
    acc01 = __builtin_amdgcn_mfma_f32_32x32x16_bf16(f0, f1, acc01, 0,0,0); \
    acc11 = __builtin_amdgcn_mfma_f32_32x32x16_bf16(f1, f1, acc11, 0,0,0); } }

  uint4 pfA[4], pfB[4];
  ISSUE(pfA, 0);
  #pragma unroll
  for (int ch=0; ch<8; ch+=2){
    if (ch+1<8) ISSUE(pfB, ch+1);
    __syncthreads();                 // prev MFMA done; pads visible on first pass
    CW(pfA);
    __syncthreads();
    MF();
    if (ch+2<8) ISSUE(pfA, ch+2);
    __syncthreads();
    CW(pfB);
    __syncthreads();
    MF();
  }
  __syncthreads();

  // cross-wave reduce (upper tiles): C layout col=lane&31, row=(reg&3)+8*(reg>>2)+4*(lane>>5)
  const int ccol = lane & 31;
  const int rbase = 4*(lane>>5);
  #pragma unroll
  for (int q2=0;q2<16;q2++){
    const int rr = (q2&3) + 8*(q2>>2) + rbase;
    atomicAdd(&red[ rr    *52 + ccol     ], acc00[q2]);
    atomicAdd(&red[ rr    *52 + 32 + ccol], acc01[q2]);
    atomicAdd(&red[(rr+32)*52 + 32 + ccol], acc11[q2]);
  }
  __syncthreads();
  float* wp = wsA + blockIdx.x * 2500;
  for (int idx=tid; idx<2500; idx+=256){
    const int i2 = idx/50, j2 = idx%50;
    wp[idx] = (i2>=32 && j2<32) ? red[j2*52+i2] : red[i2*52+j2];
  }
#undef ISSUE
#undef CW
#undef MF
}

// ---------------- spatial stage: softmax -> WT (+I folded, padded 52), c ----------------
__global__ __launch_bounds__(256) void k_s2(const float* __restrict__ wsA, float* __restrict__ wsWT, float* __restrict__ wsC){
  const int bt = blockIdx.x;
  const int tid = threadIdx.x;
  __shared__ float A[2500];
  __shared__ float m[49], r[49];
  for (int idx=tid; idx<2548; idx+=256) wsWT[bt*2548+idx] = 0.f;
  for (int idx=tid; idx<2500; idx+=256){
    float v = 0.f;
    #pragma unroll
    for (int sl=0; sl<4; sl++) v += wsA[(bt*4+sl)*2500 + idx];
    A[idx] = v;
  }
  __syncthreads();
  if (tid < 49){
    const float mm = A[49*50+tid] * (1.f/4096.f);        // row 49 = ones row -> sums
    const float var = A[tid*50+tid] * (1.f/4096.f) - mm*mm;
    m[tid]=mm; r[tid]=rsqrtf(var+1e-5f);
  }
  __syncthreads();
  const int wv = tid>>6, lane = tid&63;
  for (int i=wv; i<49; i+=4){
    const float ri = r[i], mi = m[i];
    float rv=0.f, mv=0.f, L=-1e30f;
    if (lane < 49){
      rv = r[lane]; mv = m[lane];
      L = ri*rv*(A[i*50+lane] - 4096.f*mi*mv) * (1.f/64.f);
    }
    float mx = L;
    #pragma unroll
    for (int off=32; off; off>>=1) mx = fmaxf(mx, __shfl_xor(mx, off));
    const float p = (lane<49) ? __expf(L-mx) : 0.f;
    const float ss = wsum64(p);
    const float Wv = (p/ss)*rv;
    // WT[j=lane][i] = W[i][j] + I
    if (lane < 49) wsWT[bt*2548 + lane*52 + i] = Wv + ((lane==i) ? 1.f : 0.f);
    const float cp = wsum64(-Wv*mv);
    if (lane == 0) wsC[bt*49+i] = cp;
  }
}

// ---------------- spatial stage: recombine via MFMA, B-frags direct from global (R14 body) ----------------
// O = Wp*Y + c. Single bf16 Y plane: 25 ushort loads + 16 MFMA per tile. (256,2): proven
// no-spill point (VGPR 92); (256,4) forces 64-reg cap + scratch spill (R17).
__global__ __launch_bounds__(256,2) void k_s3(const unsigned short* __restrict__ y1u, const float* __restrict__ wsWT,
                                              const float* __restrict__ wsC, float* __restrict__ out){
  const int bt = blockIdx.x >> 3;
  const int chunk = blockIdx.x & 7;       // 512 e-cols per block
  const int tid = threadIdx.x;
  const int wave = tid >> 6, lane = tid & 63;

  __shared__ unsigned short Wh[64*68], Wlo[64*68];
  for (int idx=tid; idx<64*64; idx+=256){
    const int i = idx>>6, j = idx&63;
    float v = 0.f;
    if (i < 49){
      if (j < 49)       v = wsWT[bt*2548 + j*52 + i];   // W[i][j]+I
      else if (j == 49) v = wsC[bt*49 + i];             // c[i]
    }
    const unsigned int u = __float_as_uint(v);
    Wh [i*68+j] = (unsigned short)(u>>16);
    Wlo[i*68+j] = (unsigned short)rne_bf16(v - __uint_as_float(u & 0xFFFF0000u));
  }
  __syncthreads();

  const int r0 = lane & 31;
  const int koff = (lane >> 5) * 8;
  bf16x8 A0h[4], A0l[4], A1h[4], A1l[4];
  #pragma unroll
  for (int kk=0;kk<4;kk++){
    const int off = kk*16 + koff;
    A0h[kk] = *reinterpret_cast<const bf16x8*>(&Wh [ r0     *68 + off]);
    A0l[kk] = *reinterpret_cast<const bf16x8*>(&Wlo[ r0     *68 + off]);
    A1h[kk] = *reinterpret_cast<const bf16x8*>(&Wh [(32+r0)*68 + off]);
    A1l[kk] = *reinterpret_cast<const bf16x8*>(&Wlo[(32+r0)*68 + off]);
  }

  const unsigned short* ybu = y1u + (size_t)bt*49*YP;
  float* ob_base = out + bt*200704;
  const bool lo32 = (lane < 32);

  #pragma unroll
  for (int tt=0; tt<4; tt++){
    const int ecol = chunk*512 + (wave*4+tt)*32 + r0;
    const unsigned short* pb = ybu + (size_t)koff*YP + ecol;   // per-lane base at j=koff

    f32x16 acc0, acc1;
    #pragma unroll
    for (int i=0;i<16;i++){ acc0[i]=0.f; acc1[i]=0.f; }

    #pragma unroll
    for (int kk=0;kk<4;kk++){
      bf16x8 Bh;
      if (kk < 3){
        #pragma unroll
        for (int s=0;s<8;s++)             // j = kk*16 + koff + s  (max 47 < 49)
          Bh[s] = (short)pb[(size_t)(kk*16+s)*YP];
      } else {
        // lanes<32: j=48 (load), j=49 (ones: folds c); lanes>=32: all zero
        const unsigned short h48 = lo32 ? pb[(size_t)48*YP] : (unsigned short)0;
        Bh[0] = (short)h48;
        Bh[1] = lo32 ? (short)0x3F80 : (short)0;
        #pragma unroll
        for (int s=2;s<8;s++) Bh[s]=0;
      }
      acc0 = __builtin_amdgcn_mfma_f32_32x32x16_bf16(A0h[kk], Bh, acc0, 0,0,0);
      acc0 = __builtin_amdgcn_mfma_f32_32x32x16_bf16(A0l[kk], Bh, acc0, 0,0,0);
      acc1 = __builtin_amdgcn_mfma_f32_32x32x16_bf16(A1h[kk], Bh, acc1, 0,0,0);
      acc1 = __builtin_amdgcn_mfma_f32_32x32x16_bf16(A1l[kk], Bh, acc1, 0,0,0);
    }

    // store: C layout col=lane&31, row=(reg&3)+8*(reg>>2)+4*(lane>>5)
    const int c  = ecol >> 4;
    const int p1 = (ecol >> 2) & 3;
    const int p2 = ecol & 3;
    float* ob = ob_base + c*784 + p1*28 + p2;
    const int rbase = 4*(lane>>5);
    #pragma unroll
    for (int q=0;q<16;q++){
      const int i0 = (q&3) + 8*(q>>2) + rbase;       // 0..31
      ob[(i0/7)*112 + (i0%7)*4] = acc0[q];
      const int i1 = 32 + i0;
      if (i1 < 49) ob[(i1/7)*112 + (i1%7)*4] = acc1[q];
    }
  }
}

extern "C" void kernel_launch(void* const* d_in, const int* in_sizes, int n_in,
                              void* d_out, int out_size, void* d_ws, size_t ws_size,
                              hipStream_t stream) {
  const float* x = (const float*)d_in[0];
  float* out = (float*)d_out;
  float* ws  = (float*)d_ws;
  unsigned short* y1u = (unsigned short*)ws;  // 6272 rows * 4128 bf16 = 51.8 MB
  float* wsA  = ws + 13000000;          // 512*2500 = 1,280,000 floats (after y1u + slack)
  float* wsWT = wsA + 512*2500;         // 128*2548 = 326,144 floats (W^T + I, padded 52)
  float* wsC  = wsWT + 128*2548;        // 128*49   -> total ~58.6 MB (well within ws)
  // overlay (dead before k_s1 writes wsA): temporal Gram partials + per-seq W
  float* wsG  = wsA;                    // 784*16*44 = 551,936 floats
  float* wsWt = wsA + 551936;           // 784*72   =  56,448 floats (fits in wsA)
  hipLaunchKernelGGL(k_t1, dim3(1792), dim3(256), 0, stream, x, wsG);
  hipLaunchKernelGGL(k_t2, dim3(784),  dim3(64),  0, stream, wsG, wsWt);
  hipLaunchKernelGGL(k_t3, dim3(1792), dim3(256), 0, stream, x, wsWt, y1u);
  hipLaunchKernelGGL(k_s1, dim3(512),  dim3(256), 0, stream, y1u, wsA);
  hipLaunchKernelGGL(k_s2, dim3(128),  dim3(256), 0, stream, wsA, wsWT, wsC);
  hipLaunchKernelGGL(k_s3, dim3(1024), dim3(256), 0, stream, y1u, wsWT, wsC, out);
}